// Round 1
// baseline (1684.588 us; speedup 1.0000x reference)
//
#include <hip/hip_runtime.h>

#define T_SEQ 2048
#define C_DIM 1024
#define H_N   16
#define HS_D  64
#define V_DIM 32000

typedef float f32x4 __attribute__((ext_vector_type(4)));
typedef __bf16 bf16x8 __attribute__((ext_vector_type(8)));
typedef unsigned short us4 __attribute__((ext_vector_type(4)));

__device__ inline unsigned short f2bf(float f) {
  unsigned int u = __float_as_uint(f);
  u = (u + 0x7FFFu + ((u >> 16) & 1u)) >> 16;
  return (unsigned short)u;
}

// ---------------- embed: h = tok_emb[x] + pos_emb, cast to bf16 ----------------
__global__ __launch_bounds__(256) void embed_kernel(
    const int* __restrict__ x, const float* __restrict__ tok,
    const float* __restrict__ pos, unsigned short* __restrict__ h) {
  int idx = blockIdx.x * 256 + threadIdx.x;   // over (B*T*C)/4
  int bt = idx >> 8;                          // 256 float4 per row
  int c4 = (idx & 255) * 4;
  int t = bt & (T_SEQ - 1);
  int tokid = x[bt];
  f32x4 a = *(const f32x4*)(tok + (size_t)tokid * C_DIM + c4);
  f32x4 b = *(const f32x4*)(pos + (size_t)t * C_DIM + c4);
  f32x4 s = a + b;
  us4 o;
  o[0] = f2bf(s[0]); o[1] = f2bf(s[1]); o[2] = f2bf(s[2]); o[3] = f2bf(s[3]);
  *(us4*)(h + (size_t)bt * C_DIM + c4) = o;
}

// ------------- repack wq/wk/wv [H,C,HS] f32 -> bf16 [3072][1024] (N,K) -------------
__global__ __launch_bounds__(256) void repack_qkv(
    const float* __restrict__ wq, const float* __restrict__ wk, const float* __restrict__ wv,
    const float* __restrict__ bq, const float* __restrict__ bk, const float* __restrict__ bv,
    unsigned short* __restrict__ wt, float* __restrict__ biasp) {
  int which = blockIdx.y;
  const float* w = (which == 0) ? wq : (which == 1) ? wk : wv;
  int i = blockIdx.x * 256 + threadIdx.x;   // 0 .. H*C*HS (=1M)
  int d = i & 63;
  int c = (i >> 6) & (C_DIM - 1);
  int hh = i >> 16;
  int n = which * 1024 + hh * 64 + d;
  wt[(size_t)n * C_DIM + c] = f2bf(w[i]);
  if (c == 0) {
    const float* bb = (which == 0) ? bq : (which == 1) ? bk : bv;
    biasp[n] = bb[hh * 64 + d];
  }
}

// ------------- transpose-repack w_head [C,V] f32 -> bf16 [V][C] -------------
__global__ __launch_bounds__(256) void repack_whead(
    const float* __restrict__ wh, unsigned short* __restrict__ wht) {
  __shared__ float tile[64][65];
  int v0 = blockIdx.x * 64;
  int c0 = blockIdx.y * 64;
  int tr = threadIdx.x >> 6;      // 0..3
  int tc = threadIdx.x & 63;
#pragma unroll
  for (int i = 0; i < 16; ++i) {
    int r = i * 4 + tr;
    tile[r][tc] = wh[(size_t)(c0 + r) * V_DIM + v0 + tc];
  }
  __syncthreads();
#pragma unroll
  for (int i = 0; i < 16; ++i) {
    int vr = i * 4 + tr;
    wht[(size_t)(v0 + vr) * C_DIM + c0 + tc] = f2bf(tile[tc][vr]);
  }
}

// ------------- GEMM: C[M][N] = A[M][K=1024] (bf16) x Bt[N][K] (bf16) + bias[N] -------------
__global__ __launch_bounds__(256) void gemm_bf16(
    const unsigned short* __restrict__ A, const unsigned short* __restrict__ Bt,
    const float* __restrict__ bias, float* __restrict__ Cout, int N) {
  const int K = 1024;
  __shared__ unsigned short As[128 * 32];
  __shared__ unsigned short Bs[128 * 32];
  int tid = threadIdx.x;
  int lane = tid & 63, wv = tid >> 6;
  int m0 = blockIdx.y * 128, n0 = blockIdx.x * 128;
  int wm = (wv >> 1) * 64, wn = (wv & 1) * 64;
  int r16 = lane & 15, g = lane >> 4;
  f32x4 acc[4][4] = {};

  for (int k0 = 0; k0 < K; k0 += 32) {
#pragma unroll
    for (int it = 0; it < 2; ++it) {
      int ch = it * 256 + wv * 64 + lane;
      int row = ch >> 2, cc = (ch & 3) * 8;
      const unsigned short* ga = A + (size_t)(m0 + row) * K + k0 + cc;
      __builtin_amdgcn_global_load_lds(
          (const __attribute__((address_space(1))) void*)ga,
          (__attribute__((address_space(3))) void*)&As[ch * 8], 16, 0, 0);
      const unsigned short* gb = Bt + (size_t)(n0 + row) * K + k0 + cc;
      __builtin_amdgcn_global_load_lds(
          (const __attribute__((address_space(1))) void*)gb,
          (__attribute__((address_space(3))) void*)&Bs[ch * 8], 16, 0, 0);
    }
    __syncthreads();
    bf16x8 fa[4], fb[4];
#pragma unroll
    for (int m = 0; m < 4; ++m)
      fa[m] = *(const bf16x8*)&As[(wm + m * 16 + r16) * 32 + g * 8];
#pragma unroll
    for (int n = 0; n < 4; ++n)
      fb[n] = *(const bf16x8*)&Bs[(wn + n * 16 + r16) * 32 + g * 8];
#pragma unroll
    for (int m = 0; m < 4; ++m)
#pragma unroll
      for (int n = 0; n < 4; ++n)
        acc[m][n] = __builtin_amdgcn_mfma_f32_16x16x32_bf16(fa[m], fb[n], acc[m][n], 0, 0, 0);
    __syncthreads();
  }
#pragma unroll
  for (int m = 0; m < 4; ++m) {
    int row = m0 + wm + m * 16 + g * 4;
#pragma unroll
    for (int n = 0; n < 4; ++n) {
      int col = n0 + wn + n * 16 + r16;
      float bv = bias[col];
#pragma unroll
      for (int j = 0; j < 4; ++j)
        Cout[(size_t)(row + j) * N + col] = acc[m][n][j] + bv;
    }
  }
}

// ------------- causal attention, vector f32, online softmax -------------
// qkv layout: [B*T][3072], q cols 0..1023 (=h*64+d), k cols 1024.., v cols 2048..
__global__ __launch_bounds__(256) void attn_kernel(
    const float* __restrict__ qkv, unsigned short* __restrict__ y) {
  __shared__ float Ks[64][68];
  __shared__ float Vs[64][68];
  int bh = blockIdx.y;
  int b = bh >> 4, h = bh & 15;
  int qb = blockIdx.x;
  int tid = threadIdx.x;
  int qi = tid >> 2, kq = tid & 3;
  int qrow = qb * 64 + qi;
  const float* qptr = qkv + ((size_t)(b * T_SEQ) + qrow) * 3072 + h * 64;
  f32x4 q[16];
#pragma unroll
  for (int c = 0; c < 16; ++c) q[c] = *(const f32x4*)(qptr + c * 4);
  f32x4 yacc[16] = {};
  float mrun = -INFINITY, lrun = 0.f;
  const float scale = 0.03125f;  // 1024^-0.5
  int srow = tid >> 2;

  for (int kb = 0; kb <= qb; ++kb) {
    const float* kbase = qkv + ((size_t)(b * T_SEQ) + kb * 64 + srow) * 3072 + 1024 + h * 64;
#pragma unroll
    for (int i = 0; i < 4; ++i) {
      int ch = i * 4 + (tid & 3);
      *(f32x4*)&Ks[srow][ch * 4] = *(const f32x4*)(kbase + ch * 4);
      *(f32x4*)&Vs[srow][ch * 4] = *(const f32x4*)(kbase + 1024 + ch * 4);
    }
    __syncthreads();
    float p[16];
    float mloc = -INFINITY;
#pragma unroll
    for (int j = 0; j < 16; ++j) {
      int key = j * 4 + kq;
      f32x4 a = {};
#pragma unroll
      for (int c = 0; c < 16; ++c) a += q[c] * *(const f32x4*)&Ks[key][c * 4];
      float s = (a[0] + a[1] + a[2] + a[3]) * scale;
      if (kb == qb && (kb * 64 + key) > qrow) s = -INFINITY;
      p[j] = s;
      mloc = fmaxf(mloc, s);
    }
    mloc = fmaxf(mloc, __shfl_xor(mloc, 1));
    mloc = fmaxf(mloc, __shfl_xor(mloc, 2));
    float mnew = fmaxf(mrun, mloc);
    float corr = __expf(mrun - mnew);   // mrun=-inf -> 0 on first block
    float psum = 0.f;
#pragma unroll
    for (int j = 0; j < 16; ++j) { p[j] = __expf(p[j] - mnew); psum += p[j]; }
    lrun = lrun * corr + psum;
#pragma unroll
    for (int c = 0; c < 16; ++c) yacc[c] *= corr;
#pragma unroll
    for (int j = 0; j < 16; ++j) {
      int key = j * 4 + kq;
      float pj = p[j];
#pragma unroll
      for (int c = 0; c < 16; ++c) yacc[c] += pj * *(const f32x4*)&Vs[key][c * 4];
    }
    mrun = mnew;
    __syncthreads();
  }
  lrun += __shfl_xor(lrun, 1);
  lrun += __shfl_xor(lrun, 2);
#pragma unroll
  for (int c = 0; c < 16; ++c) {
#pragma unroll
    for (int w = 0; w < 4; ++w) {
      float v = yacc[c][w];
      v += __shfl_xor(v, 1);
      v += __shfl_xor(v, 2);
      yacc[c][w] = v;
    }
  }
  if (kq == 0) {
    float inv = 1.f / lrun;
    unsigned short* yo = y + ((size_t)(b * T_SEQ) + qrow) * C_DIM + h * 64;
#pragma unroll
    for (int c = 0; c < 16; ++c) {
      us4 o;
      o[0] = f2bf(yacc[c][0] * inv);
      o[1] = f2bf(yacc[c][1] * inv);
      o[2] = f2bf(yacc[c][2] * inv);
      o[3] = f2bf(yacc[c][3] * inv);
      *(us4*)(yo + c * 4) = o;
    }
  }
}

extern "C" void kernel_launch(void* const* d_in, const int* in_sizes, int n_in,
                              void* d_out, int out_size, void* d_ws, size_t ws_size,
                              hipStream_t stream) {
  const int*   x    = (const int*)d_in[0];
  const float* tok  = (const float*)d_in[1];
  const float* pos  = (const float*)d_in[2];
  const float* wq   = (const float*)d_in[3];
  const float* bq   = (const float*)d_in[4];
  const float* wk   = (const float*)d_in[5];
  const float* bk   = (const float*)d_in[6];
  const float* wv   = (const float*)d_in[7];
  const float* bv   = (const float*)d_in[8];
  const float* wh   = (const float*)d_in[9];
  const float* bhd  = (const float*)d_in[10];
  float* out = (float*)d_out;

  char* ws = (char*)d_ws;
  size_t off = 0;
  auto alloc = [&](size_t bytes) {
    void* p = ws + off;
    off += (bytes + 255) & ~(size_t)255;
    return p;
  };
  unsigned short* h_bf    = (unsigned short*)alloc((size_t)4096 * 1024 * 2);
  unsigned short* wqkv_t  = (unsigned short*)alloc((size_t)3072 * 1024 * 2);
  float*          qbias   = (float*)alloc((size_t)3072 * 4);
  unsigned short* wh_t    = (unsigned short*)alloc((size_t)V_DIM * 1024 * 2);
  float*          qkv     = (float*)alloc((size_t)4096 * 3072 * 4);
  unsigned short* ybf     = (unsigned short*)alloc((size_t)4096 * 1024 * 2);

  embed_kernel<<<4096, 256, 0, stream>>>(x, tok, pos, h_bf);
  repack_qkv<<<dim3(4096, 3), 256, 0, stream>>>(wq, wk, wv, bq, bk, bv, wqkv_t, qbias);
  repack_whead<<<dim3(V_DIM / 64, 16), 256, 0, stream>>>(wh, wh_t);
  gemm_bf16<<<dim3(3072 / 128, 4096 / 128), 256, 0, stream>>>(h_bf, wqkv_t, qbias, qkv, 3072);
  attn_kernel<<<dim3(T_SEQ / 64, 2 * H_N), 256, 0, stream>>>(qkv, ybf);
  gemm_bf16<<<dim3(V_DIM / 128, 4096 / 128), 256, 0, stream>>>(ybf, wh_t, bhd, out, V_DIM);
}

// Round 2
// 713.676 us; speedup vs baseline: 2.3604x; 2.3604x over previous
//
#include <hip/hip_runtime.h>

#define T_SEQ 2048
#define C_DIM 1024
#define H_N   16
#define HS_D  64
#define V_DIM 32000

typedef float f32x4 __attribute__((ext_vector_type(4)));
typedef __bf16 bf16x8 __attribute__((ext_vector_type(8)));
typedef unsigned short us4 __attribute__((ext_vector_type(4)));
typedef unsigned short us8 __attribute__((ext_vector_type(8)));

__device__ inline unsigned short f2bf(float f) {
  unsigned int u = __float_as_uint(f);
  u = (u + 0x7FFFu + ((u >> 16) & 1u)) >> 16;
  return (unsigned short)u;
}

// ---------------- embed: h = tok_emb[x] + pos_emb, cast to bf16 ----------------
__global__ __launch_bounds__(256) void embed_kernel(
    const int* __restrict__ x, const float* __restrict__ tok,
    const float* __restrict__ pos, unsigned short* __restrict__ h) {
  int idx = blockIdx.x * 256 + threadIdx.x;   // over (B*T*C)/4
  int bt = idx >> 8;                          // 256 float4 per row
  int c4 = (idx & 255) * 4;
  int t = bt & (T_SEQ - 1);
  int tokid = x[bt];
  f32x4 a = *(const f32x4*)(tok + (size_t)tokid * C_DIM + c4);
  f32x4 b = *(const f32x4*)(pos + (size_t)t * C_DIM + c4);
  f32x4 s = a + b;
  us4 o;
  o[0] = f2bf(s[0]); o[1] = f2bf(s[1]); o[2] = f2bf(s[2]); o[3] = f2bf(s[3]);
  *(us4*)(h + (size_t)bt * C_DIM + c4) = o;
}

// ------------- repack wq/wk/wv [H,C,HS] f32 -> bf16 [3072][1024] (N,K) -------------
__global__ __launch_bounds__(256) void repack_qkv(
    const float* __restrict__ wq, const float* __restrict__ wk, const float* __restrict__ wv,
    const float* __restrict__ bq, const float* __restrict__ bk, const float* __restrict__ bv,
    unsigned short* __restrict__ wt, float* __restrict__ biasp) {
  int which = blockIdx.y;
  const float* w = (which == 0) ? wq : (which == 1) ? wk : wv;
  int i = blockIdx.x * 256 + threadIdx.x;   // 0 .. H*C*HS (=1M)
  int d = i & 63;
  int c = (i >> 6) & (C_DIM - 1);
  int hh = i >> 16;
  int n = which * 1024 + hh * 64 + d;
  wt[(size_t)n * C_DIM + c] = f2bf(w[i]);
  if (c == 0) {
    const float* bb = (which == 0) ? bq : (which == 1) ? bk : bv;
    biasp[n] = bb[hh * 64 + d];
  }
}

// ------------- transpose-repack w_head [C,V] f32 -> bf16 [V][C] -------------
__global__ __launch_bounds__(256) void repack_whead(
    const float* __restrict__ wh, unsigned short* __restrict__ wht) {
  __shared__ float tile[64][65];
  int v0 = blockIdx.x * 64;
  int c0 = blockIdx.y * 64;
  int tr = threadIdx.x >> 6;      // 0..3
  int tc = threadIdx.x & 63;
#pragma unroll
  for (int i = 0; i < 16; ++i) {
    int r = i * 4 + tr;
    tile[r][tc] = wh[(size_t)(c0 + r) * V_DIM + v0 + tc];
  }
  __syncthreads();
#pragma unroll
  for (int i = 0; i < 16; ++i) {
    int vr = i * 4 + tr;
    wht[(size_t)(v0 + vr) * C_DIM + c0 + tc] = f2bf(tile[tc][vr]);
  }
}

// ------------- GEMM: C[M][N] = A[M][K=1024] (bf16) x Bt[N][K] (bf16) + bias[N] -------------
__global__ __launch_bounds__(256) void gemm_bf16(
    const unsigned short* __restrict__ A, const unsigned short* __restrict__ Bt,
    const float* __restrict__ bias, float* __restrict__ Cout, int N) {
  const int K = 1024;
  __shared__ unsigned short As[128 * 32];
  __shared__ unsigned short Bs[128 * 32];
  int tid = threadIdx.x;
  int lane = tid & 63, wv = tid >> 6;
  int m0 = blockIdx.y * 128, n0 = blockIdx.x * 128;
  int wm = (wv >> 1) * 64, wn = (wv & 1) * 64;
  int r16 = lane & 15, g = lane >> 4;
  f32x4 acc[4][4] = {};

  for (int k0 = 0; k0 < K; k0 += 32) {
#pragma unroll
    for (int it = 0; it < 2; ++it) {
      int ch = it * 256 + wv * 64 + lane;
      int row = ch >> 2, cc = (ch & 3) * 8;
      const unsigned short* ga = A + (size_t)(m0 + row) * K + k0 + cc;
      __builtin_amdgcn_global_load_lds(
          (const __attribute__((address_space(1))) void*)ga,
          (__attribute__((address_space(3))) void*)&As[ch * 8], 16, 0, 0);
      const unsigned short* gb = Bt + (size_t)(n0 + row) * K + k0 + cc;
      __builtin_amdgcn_global_load_lds(
          (const __attribute__((address_space(1))) void*)gb,
          (__attribute__((address_space(3))) void*)&Bs[ch * 8], 16, 0, 0);
    }
    __syncthreads();
    bf16x8 fa[4], fb[4];
#pragma unroll
    for (int m = 0; m < 4; ++m)
      fa[m] = *(const bf16x8*)&As[(wm + m * 16 + r16) * 32 + g * 8];
#pragma unroll
    for (int n = 0; n < 4; ++n)
      fb[n] = *(const bf16x8*)&Bs[(wn + n * 16 + r16) * 32 + g * 8];
#pragma unroll
    for (int m = 0; m < 4; ++m)
#pragma unroll
      for (int n = 0; n < 4; ++n)
        acc[m][n] = __builtin_amdgcn_mfma_f32_16x16x32_bf16(fa[m], fb[n], acc[m][n], 0, 0, 0);
    __syncthreads();
  }
#pragma unroll
  for (int m = 0; m < 4; ++m) {
    int row = m0 + wm + m * 16 + g * 4;
#pragma unroll
    for (int n = 0; n < 4; ++n) {
      int col = n0 + wn + n * 16 + r16;
      float bv = bias[col];
#pragma unroll
      for (int j = 0; j < 4; ++j)
        Cout[(size_t)(row + j) * N + col] = acc[m][n][j] + bv;
    }
  }
}

// ------------- MFMA flash attention -------------
// qkv: [B*T][3072] f32 (q | k | v, each [h][64]).  y: [B*T][1024] bf16.
// Block = 4 waves, one 64-query tile of one (b,h). KV tiles of 64 keys.
// LDS: K [64 keys][64 hs] bf16 swizzled; Vt [64 ch][64 keys] bf16 swizzled;
//      P [64 q][64 keys] bf16 swizzled (wave-private strips).
__global__ __launch_bounds__(256) void attn_mfma(
    const float* __restrict__ qkv, unsigned short* __restrict__ y) {
  __shared__ char lds[24576];
  char* Kl = lds;
  char* Vl = lds + 8192;
  char* Pl = lds + 16384;

  int bh = blockIdx.y;
  int b = bh >> 4, h = bh & 15;
  int qb = (T_SEQ / 64 - 1) - blockIdx.x;   // big tiles first (tail balance)
  int tid = threadIdx.x;
  int lane = tid & 63, w = tid >> 6;
  int l16 = lane & 15, g = lane >> 4;
  size_t bT = (size_t)b * T_SEQ;
  const float scale = 0.03125f;  // 1024^-0.5

  // Q fragments: A rows = w*16 + l16, k = kk*32 + g*8 + i
  bf16x8 qf[2];
  {
    const float* qrow = qkv + (bT + qb * 64 + w * 16 + l16) * 3072 + h * 64;
#pragma unroll
    for (int kk = 0; kk < 2; ++kk) {
      f32x4 a = *(const f32x4*)(qrow + kk * 32 + g * 8);
      f32x4 c = *(const f32x4*)(qrow + kk * 32 + g * 8 + 4);
      us8 o;
      o[0] = f2bf(a[0]); o[1] = f2bf(a[1]); o[2] = f2bf(a[2]); o[3] = f2bf(a[3]);
      o[4] = f2bf(c[0]); o[5] = f2bf(c[1]); o[6] = f2bf(c[2]); o[7] = f2bf(c[3]);
      qf[kk] = *(bf16x8*)&o;
    }
  }

  f32x4 yacc[4] = {};             // [n ch-tile][j row]
  float mrun[4], lrun[4];
#pragma unroll
  for (int j = 0; j < 4; ++j) { mrun[j] = -3.0e38f; lrun[j] = 0.f; }

  int srow = tid >> 2;            // staging: key row
  int c0 = (tid & 3) * 16;        // staging: col group

  for (int kb = 0; kb <= qb; ++kb) {
    // ---- stage K and V^T (bf16, swizzled) ----
    {
      const float* kp = qkv + (bT + kb * 64 + srow) * 3072 + 1024 + h * 64 + c0;
      f32x4 k0 = *(const f32x4*)(kp + 0);
      f32x4 k1 = *(const f32x4*)(kp + 4);
      f32x4 k2 = *(const f32x4*)(kp + 8);
      f32x4 k3 = *(const f32x4*)(kp + 12);
      us8 pa, pb;
      pa[0]=f2bf(k0[0]); pa[1]=f2bf(k0[1]); pa[2]=f2bf(k0[2]); pa[3]=f2bf(k0[3]);
      pa[4]=f2bf(k1[0]); pa[5]=f2bf(k1[1]); pa[6]=f2bf(k1[2]); pa[7]=f2bf(k1[3]);
      pb[0]=f2bf(k2[0]); pb[1]=f2bf(k2[1]); pb[2]=f2bf(k2[2]); pb[3]=f2bf(k2[3]);
      pb[4]=f2bf(k3[0]); pb[5]=f2bf(k3[1]); pb[6]=f2bf(k3[2]); pb[7]=f2bf(k3[3]);
      *(us8*)(Kl + ((srow * 128 + c0 * 2)      ^ ((srow & 7) << 4))) = pa;
      *(us8*)(Kl + ((srow * 128 + c0 * 2 + 16) ^ ((srow & 7) << 4))) = pb;
      const float* vp = kp + 1024;
      f32x4 v0 = *(const f32x4*)(vp + 0);
      f32x4 v1 = *(const f32x4*)(vp + 4);
      f32x4 v2 = *(const f32x4*)(vp + 8);
      f32x4 v3 = *(const f32x4*)(vp + 12);
      float vals[16] = {v0[0],v0[1],v0[2],v0[3], v1[0],v1[1],v1[2],v1[3],
                        v2[0],v2[1],v2[2],v2[3], v3[0],v3[1],v3[2],v3[3]};
#pragma unroll
      for (int i = 0; i < 16; ++i) {
        int ch = c0 + i;
        *(unsigned short*)(Vl + ((ch * 128 + srow * 2) ^ ((ch & 7) << 4))) = f2bf(vals[i]);
      }
    }
    __syncthreads();

    // ---- S = Q K^T (wave strip: 16 q-rows x 64 keys) ----
    f32x4 s[4] = {};
#pragma unroll
    for (int kk = 0; kk < 2; ++kk)
#pragma unroll
      for (int n = 0; n < 4; ++n) {
        int krow = n * 16 + l16;
        bf16x8 fb = *(const bf16x8*)(Kl + ((krow * 128 + (kk * 32 + g * 8) * 2) ^ ((krow & 7) << 4)));
        s[n] = __builtin_amdgcn_mfma_f32_16x16x32_bf16(qf[kk], fb, s[n], 0, 0, 0);
      }

    // ---- online softmax (rows = g*4+j within strip, cols = n*16+l16) ----
    bool diag = (kb == qb);
    float pr[4][4];                 // [n][j]
    float corr[4];
#pragma unroll
    for (int j = 0; j < 4; ++j) {
      int rloc = w * 16 + g * 4 + j;   // row in 64-tile
      float m = -3.0e38f;
#pragma unroll
      for (int n = 0; n < 4; ++n) {
        float v = s[n][j] * scale;
        if (diag && (n * 16 + l16) > rloc) v = -3.0e38f;
        pr[n][j] = v;
        m = fmaxf(m, v);
      }
      m = fmaxf(m, __shfl_xor(m, 1));
      m = fmaxf(m, __shfl_xor(m, 2));
      m = fmaxf(m, __shfl_xor(m, 4));
      m = fmaxf(m, __shfl_xor(m, 8));
      float mn = fmaxf(mrun[j], m);
      corr[j] = __expf(mrun[j] - mn);
      mrun[j] = mn;
      float ps = 0.f;
#pragma unroll
      for (int n = 0; n < 4; ++n) {
        float e = __expf(pr[n][j] - mn);
        pr[n][j] = e;
        ps += e;
      }
      ps += __shfl_xor(ps, 1);
      ps += __shfl_xor(ps, 2);
      ps += __shfl_xor(ps, 4);
      ps += __shfl_xor(ps, 8);
      lrun[j] = lrun[j] * corr[j] + ps;
    }
#pragma unroll
    for (int n = 0; n < 4; ++n)
#pragma unroll
      for (int j = 0; j < 4; ++j)
        yacc[n][j] *= corr[j];

    // ---- write P strip (wave-private) ----
#pragma unroll
    for (int j = 0; j < 4; ++j) {
      int row = w * 16 + g * 4 + j;
#pragma unroll
      for (int n = 0; n < 4; ++n)
        *(unsigned short*)(Pl + ((row * 128 + (n * 16 + l16) * 2) ^ ((row & 7) << 4))) = f2bf(pr[n][j]);
    }

    // ---- y += P V ----
#pragma unroll
    for (int kk = 0; kk < 2; ++kk) {
      int prow = w * 16 + l16;
      bf16x8 fa = *(const bf16x8*)(Pl + ((prow * 128 + (kk * 32 + g * 8) * 2) ^ ((prow & 7) << 4)));
#pragma unroll
      for (int n = 0; n < 4; ++n) {
        int vrow = n * 16 + l16;
        bf16x8 fb = *(const bf16x8*)(Vl + ((vrow * 128 + (kk * 32 + g * 8) * 2) ^ ((vrow & 7) << 4)));
        yacc[n] = __builtin_amdgcn_mfma_f32_16x16x32_bf16(fa, fb, yacc[n], 0, 0, 0);
      }
    }
    __syncthreads();
  }

  // ---- output ----
#pragma unroll
  for (int j = 0; j < 4; ++j) {
    float inv = 1.0f / lrun[j];
    int row = qb * 64 + w * 16 + g * 4 + j;
    unsigned short* yo = y + (bT + row) * C_DIM + h * 64;
#pragma unroll
    for (int n = 0; n < 4; ++n)
      yo[n * 16 + l16] = f2bf(yacc[n][j] * inv);
  }
}

extern "C" void kernel_launch(void* const* d_in, const int* in_sizes, int n_in,
                              void* d_out, int out_size, void* d_ws, size_t ws_size,
                              hipStream_t stream) {
  const int*   x    = (const int*)d_in[0];
  const float* tok  = (const float*)d_in[1];
  const float* pos  = (const float*)d_in[2];
  const float* wq   = (const float*)d_in[3];
  const float* bq   = (const float*)d_in[4];
  const float* wk   = (const float*)d_in[5];
  const float* bk   = (const float*)d_in[6];
  const float* wv   = (const float*)d_in[7];
  const float* bv   = (const float*)d_in[8];
  const float* wh   = (const float*)d_in[9];
  const float* bhd  = (const float*)d_in[10];
  float* out = (float*)d_out;

  char* ws = (char*)d_ws;
  size_t off = 0;
  auto alloc = [&](size_t bytes) {
    void* p = ws + off;
    off += (bytes + 255) & ~(size_t)255;
    return p;
  };
  unsigned short* h_bf    = (unsigned short*)alloc((size_t)4096 * 1024 * 2);
  unsigned short* wqkv_t  = (unsigned short*)alloc((size_t)3072 * 1024 * 2);
  float*          qbias   = (float*)alloc((size_t)3072 * 4);
  unsigned short* wh_t    = (unsigned short*)alloc((size_t)V_DIM * 1024 * 2);
  float*          qkv     = (float*)alloc((size_t)4096 * 3072 * 4);
  unsigned short* ybf     = (unsigned short*)alloc((size_t)4096 * 1024 * 2);

  embed_kernel<<<4096, 256, 0, stream>>>(x, tok, pos, h_bf);
  repack_qkv<<<dim3(4096, 3), 256, 0, stream>>>(wq, wk, wv, bq, bk, bv, wqkv_t, qbias);
  repack_whead<<<dim3(V_DIM / 64, 16), 256, 0, stream>>>(wh, wh_t);
  gemm_bf16<<<dim3(3072 / 128, 4096 / 128), 256, 0, stream>>>(h_bf, wqkv_t, qbias, qkv, 3072);
  attn_mfma<<<dim3(T_SEQ / 64, 2 * H_N), 256, 0, stream>>>(qkv, ybf);
  gemm_bf16<<<dim3(V_DIM / 128, 4096 / 128), 256, 0, stream>>>(ybf, wh_t, bhd, out, V_DIM);
}

// Round 3
// 664.858 us; speedup vs baseline: 2.5338x; 1.0734x over previous
//
#include <hip/hip_runtime.h>

#define T_SEQ 2048
#define C_DIM 1024
#define H_N   16
#define HS_D  64
#define V_DIM 32000

typedef float f32x4 __attribute__((ext_vector_type(4)));
typedef __bf16 bf16x8 __attribute__((ext_vector_type(8)));
typedef unsigned short us4 __attribute__((ext_vector_type(4)));
typedef unsigned short us8 __attribute__((ext_vector_type(8)));

__device__ inline unsigned short f2bf(float f) {
  unsigned int u = __float_as_uint(f);
  u = (u + 0x7FFFu + ((u >> 16) & 1u)) >> 16;
  return (unsigned short)u;
}

// ---------------- embed: h = tok_emb[x] + pos_emb, cast to bf16 ----------------
__global__ __launch_bounds__(256) void embed_kernel(
    const int* __restrict__ x, const float* __restrict__ tok,
    const float* __restrict__ pos, unsigned short* __restrict__ h) {
  int idx = blockIdx.x * 256 + threadIdx.x;   // over (B*T*C)/4
  int bt = idx >> 8;                          // 256 float4 per row
  int c4 = (idx & 255) * 4;
  int t = bt & (T_SEQ - 1);
  int tokid = x[bt];
  f32x4 a = *(const f32x4*)(tok + (size_t)tokid * C_DIM + c4);
  f32x4 b = *(const f32x4*)(pos + (size_t)t * C_DIM + c4);
  f32x4 s = a + b;
  us4 o;
  o[0] = f2bf(s[0]); o[1] = f2bf(s[1]); o[2] = f2bf(s[2]); o[3] = f2bf(s[3]);
  *(us4*)(h + (size_t)bt * C_DIM + c4) = o;
}

// ------------- repack wq/wk/wv [H,C,HS] f32 -> bf16 [3072][1024] (N,K) -------------
__global__ __launch_bounds__(256) void repack_qkv(
    const float* __restrict__ wq, const float* __restrict__ wk, const float* __restrict__ wv,
    const float* __restrict__ bq, const float* __restrict__ bk, const float* __restrict__ bv,
    unsigned short* __restrict__ wt, float* __restrict__ biasp) {
  int which = blockIdx.y;
  const float* w = (which == 0) ? wq : (which == 1) ? wk : wv;
  int i = blockIdx.x * 256 + threadIdx.x;   // 0 .. H*C*HS (=1M)
  int d = i & 63;
  int c = (i >> 6) & (C_DIM - 1);
  int hh = i >> 16;
  int n = which * 1024 + hh * 64 + d;
  wt[(size_t)n * C_DIM + c] = f2bf(w[i]);
  if (c == 0) {
    const float* bb = (which == 0) ? bq : (which == 1) ? bk : bv;
    biasp[n] = bb[hh * 64 + d];
  }
}

// ------------- transpose-repack w_head [C,V] f32 -> bf16 [V][C] -------------
__global__ __launch_bounds__(256) void repack_whead(
    const float* __restrict__ wh, unsigned short* __restrict__ wht) {
  __shared__ float tile[64][65];
  int v0 = blockIdx.x * 64;
  int c0 = blockIdx.y * 64;
  int tr = threadIdx.x >> 6;      // 0..3
  int tc = threadIdx.x & 63;
#pragma unroll
  for (int i = 0; i < 16; ++i) {
    int r = i * 4 + tr;
    tile[r][tc] = wh[(size_t)(c0 + r) * V_DIM + v0 + tc];
  }
  __syncthreads();
#pragma unroll
  for (int i = 0; i < 16; ++i) {
    int vr = i * 4 + tr;
    wht[(size_t)(v0 + vr) * C_DIM + c0 + tc] = f2bf(tile[tc][vr]);
  }
}

// ------------- 256x256-tile pipelined GEMM -------------
// C[M][N] = A[M][1024](bf16) x Bt[N][1024](bf16) + bias[N], f32 out.
// 8 waves (2Mx4N), BK=32, 4-deep LDS ring, counted vmcnt, raw barriers,
// XOR-swizzled LDS (pre-swizzled global source for linear global_load_lds dest).
#define GK 1024
#define GBK 32
#define GNT 32   // GK/GBK

__global__ __launch_bounds__(512, 2) void gemm256(
    const unsigned short* __restrict__ A, const unsigned short* __restrict__ Bt,
    const float* __restrict__ bias, float* __restrict__ Cout, int N, int Mtiles) {
  __shared__ unsigned short As[4][256 * 32];
  __shared__ unsigned short Bs[4][256 * 32];
  int tid = threadIdx.x;
  int lane = tid & 63;
  int wid = tid >> 6;
  int wm = wid >> 2, wn = wid & 3;
  int l16 = lane & 15, g = lane >> 4;
  int swz = (l16 & 3) ^ ((l16 >> 2) & 3);

  // XCD-bijective swizzle (gridDim.x % 8 == 0); m-tile fastest for B-panel reuse
  int cpx = gridDim.x >> 3;
  int lin = blockIdx.x;
  int wg = (lin & 7) * cpx + (lin >> 3);
  int m0 = (wg % Mtiles) * 256;
  int n0 = (wg / Mtiles) * 256;

  auto stage = [&](const unsigned short* __restrict__ G, int t0,
                   unsigned short* lds, int kt) {
#pragma unroll
    for (int L = 0; L < 2; ++L) {
      int chunk = L * 512 + tid;          // 0..1023, 16B each
      int row = chunk >> 2;
      int c = (chunk & 3) ^ (row & 3) ^ ((row >> 2) & 3);   // inverse swizzle on source
      const unsigned short* ga = G + (size_t)(t0 + row) * GK + kt * GBK + c * 8;
      __builtin_amdgcn_global_load_lds(
          (const __attribute__((address_space(1))) void*)ga,
          (__attribute__((address_space(3))) void*)(lds + chunk * 8), 16, 0, 0);
    }
  };

  // prologue: stage K-tiles 0,1,2 (12 loads/thread outstanding)
#pragma unroll
  for (int kt = 0; kt < 3; ++kt) {
    stage(A, m0, As[kt], kt);
    stage(Bt, n0, Bs[kt], kt);
  }

  f32x4 acc[8][4] = {};

  for (int t = 0; t < GNT; ++t) {
    int buf = t & 3;
    // entry wait: K-tile t fully landed (its 4 loads are the oldest); never drain
    if (t + 2 < GNT)      asm volatile("s_waitcnt vmcnt(8)" ::: "memory");
    else if (t + 1 < GNT) asm volatile("s_waitcnt vmcnt(4)" ::: "memory");
    else                  asm volatile("s_waitcnt vmcnt(0)" ::: "memory");
    asm volatile("s_barrier" ::: "memory");

    const char* Ab = (const char*)As[buf];
    const char* Bb = (const char*)Bs[buf];

    // ---- phase 0: B frags (reused both phases) + A mh=0 ----
    bf16x8 bfr[4], af[4];
#pragma unroll
    for (int n = 0; n < 4; ++n) {
      int row = wn * 64 + n * 16 + l16;
      bfr[n] = *(const bf16x8*)(Bb + row * 64 + ((g ^ swz) * 16));
    }
#pragma unroll
    for (int m = 0; m < 4; ++m) {
      int row = wm * 128 + m * 16 + l16;
      af[m] = *(const bf16x8*)(Ab + row * 64 + ((g ^ swz) * 16));
    }
    if (t + 3 < GNT) stage(A, m0, As[(t + 3) & 3], t + 3);
    __builtin_amdgcn_s_setprio(1);
#pragma unroll
    for (int m = 0; m < 4; ++m)
#pragma unroll
      for (int n = 0; n < 4; ++n)
        acc[m][n] = __builtin_amdgcn_mfma_f32_16x16x32_bf16(af[m], bfr[n], acc[m][n], 0, 0, 0);
    __builtin_amdgcn_s_setprio(0);
    asm volatile("s_barrier" ::: "memory");

    // ---- phase 1: A mh=1 ----
#pragma unroll
    for (int m = 0; m < 4; ++m) {
      int row = wm * 128 + 64 + m * 16 + l16;
      af[m] = *(const bf16x8*)(Ab + row * 64 + ((g ^ swz) * 16));
    }
    if (t + 3 < GNT) stage(Bt, n0, Bs[(t + 3) & 3], t + 3);
    __builtin_amdgcn_s_setprio(1);
#pragma unroll
    for (int m = 0; m < 4; ++m)
#pragma unroll
      for (int n = 0; n < 4; ++n)
        acc[4 + m][n] = __builtin_amdgcn_mfma_f32_16x16x32_bf16(af[m], bfr[n], acc[4 + m][n], 0, 0, 0);
    __builtin_amdgcn_s_setprio(0);
  }

  // ---- epilogue: bias + f32 store ----
#pragma unroll
  for (int m = 0; m < 8; ++m) {
    int mh = m >> 2, mi = m & 3;
    int row = m0 + wm * 128 + mh * 64 + mi * 16 + g * 4;
#pragma unroll
    for (int n = 0; n < 4; ++n) {
      int col = n0 + wn * 64 + n * 16 + l16;
      float bv = bias[col];
#pragma unroll
      for (int j = 0; j < 4; ++j)
        Cout[(size_t)(row + j) * N + col] = acc[m][n][j] + bv;
    }
  }
}

// ------------- MFMA flash attention -------------
// qkv: [B*T][3072] f32 (q | k | v, each [h][64]).  y: [B*T][1024] bf16.
__global__ __launch_bounds__(256) void attn_mfma(
    const float* __restrict__ qkv, unsigned short* __restrict__ y) {
  __shared__ char lds[24576];
  char* Kl = lds;
  char* Vl = lds + 8192;
  char* Pl = lds + 16384;

  int bh = blockIdx.y;
  int b = bh >> 4, h = bh & 15;
  int qb = (T_SEQ / 64 - 1) - blockIdx.x;   // big tiles first (tail balance)
  int tid = threadIdx.x;
  int lane = tid & 63, w = tid >> 6;
  int l16 = lane & 15, g = lane >> 4;
  size_t bT = (size_t)b * T_SEQ;
  const float scale = 0.03125f;  // 1024^-0.5

  bf16x8 qf[2];
  {
    const float* qrow = qkv + (bT + qb * 64 + w * 16 + l16) * 3072 + h * 64;
#pragma unroll
    for (int kk = 0; kk < 2; ++kk) {
      f32x4 a = *(const f32x4*)(qrow + kk * 32 + g * 8);
      f32x4 c = *(const f32x4*)(qrow + kk * 32 + g * 8 + 4);
      us8 o;
      o[0] = f2bf(a[0]); o[1] = f2bf(a[1]); o[2] = f2bf(a[2]); o[3] = f2bf(a[3]);
      o[4] = f2bf(c[0]); o[5] = f2bf(c[1]); o[6] = f2bf(c[2]); o[7] = f2bf(c[3]);
      qf[kk] = *(bf16x8*)&o;
    }
  }

  f32x4 yacc[4] = {};
  float mrun[4], lrun[4];
#pragma unroll
  for (int j = 0; j < 4; ++j) { mrun[j] = -3.0e38f; lrun[j] = 0.f; }

  int srow = tid >> 2;
  int c0 = (tid & 3) * 16;

  for (int kb = 0; kb <= qb; ++kb) {
    {
      const float* kp = qkv + (bT + kb * 64 + srow) * 3072 + 1024 + h * 64 + c0;
      f32x4 k0 = *(const f32x4*)(kp + 0);
      f32x4 k1 = *(const f32x4*)(kp + 4);
      f32x4 k2 = *(const f32x4*)(kp + 8);
      f32x4 k3 = *(const f32x4*)(kp + 12);
      us8 pa, pb;
      pa[0]=f2bf(k0[0]); pa[1]=f2bf(k0[1]); pa[2]=f2bf(k0[2]); pa[3]=f2bf(k0[3]);
      pa[4]=f2bf(k1[0]); pa[5]=f2bf(k1[1]); pa[6]=f2bf(k1[2]); pa[7]=f2bf(k1[3]);
      pb[0]=f2bf(k2[0]); pb[1]=f2bf(k2[1]); pb[2]=f2bf(k2[2]); pb[3]=f2bf(k2[3]);
      pb[4]=f2bf(k3[0]); pb[5]=f2bf(k3[1]); pb[6]=f2bf(k3[2]); pb[7]=f2bf(k3[3]);
      *(us8*)(Kl + ((srow * 128 + c0 * 2)      ^ ((srow & 7) << 4))) = pa;
      *(us8*)(Kl + ((srow * 128 + c0 * 2 + 16) ^ ((srow & 7) << 4))) = pb;
      const float* vp = kp + 1024;
      f32x4 v0 = *(const f32x4*)(vp + 0);
      f32x4 v1 = *(const f32x4*)(vp + 4);
      f32x4 v2 = *(const f32x4*)(vp + 8);
      f32x4 v3 = *(const f32x4*)(vp + 12);
      float vals[16] = {v0[0],v0[1],v0[2],v0[3], v1[0],v1[1],v1[2],v1[3],
                        v2[0],v2[1],v2[2],v2[3], v3[0],v3[1],v3[2],v3[3]};
#pragma unroll
      for (int i = 0; i < 16; ++i) {
        int ch = c0 + i;
        *(unsigned short*)(Vl + ((ch * 128 + srow * 2) ^ ((ch & 7) << 4))) = f2bf(vals[i]);
      }
    }
    __syncthreads();

    f32x4 s[4] = {};
#pragma unroll
    for (int kk = 0; kk < 2; ++kk)
#pragma unroll
      for (int n = 0; n < 4; ++n) {
        int krow = n * 16 + l16;
        bf16x8 fb = *(const bf16x8*)(Kl + ((krow * 128 + (kk * 32 + g * 8) * 2) ^ ((krow & 7) << 4)));
        s[n] = __builtin_amdgcn_mfma_f32_16x16x32_bf16(qf[kk], fb, s[n], 0, 0, 0);
      }

    bool diag = (kb == qb);
    float pr[4][4];
    float corr[4];
#pragma unroll
    for (int j = 0; j < 4; ++j) {
      int rloc = w * 16 + g * 4 + j;
      float m = -3.0e38f;
#pragma unroll
      for (int n = 0; n < 4; ++n) {
        float v = s[n][j] * scale;
        if (diag && (n * 16 + l16) > rloc) v = -3.0e38f;
        pr[n][j] = v;
        m = fmaxf(m, v);
      }
      m = fmaxf(m, __shfl_xor(m, 1));
      m = fmaxf(m, __shfl_xor(m, 2));
      m = fmaxf(m, __shfl_xor(m, 4));
      m = fmaxf(m, __shfl_xor(m, 8));
      float mn = fmaxf(mrun[j], m);
      corr[j] = __expf(mrun[j] - mn);
      mrun[j] = mn;
      float ps = 0.f;
#pragma unroll
      for (int n = 0; n < 4; ++n) {
        float e = __expf(pr[n][j] - mn);
        pr[n][j] = e;
        ps += e;
      }
      ps += __shfl_xor(ps, 1);
      ps += __shfl_xor(ps, 2);
      ps += __shfl_xor(ps, 4);
      ps += __shfl_xor(ps, 8);
      lrun[j] = lrun[j] * corr[j] + ps;
    }
#pragma unroll
    for (int n = 0; n < 4; ++n)
#pragma unroll
      for (int j = 0; j < 4; ++j)
        yacc[n][j] *= corr[j];

#pragma unroll
    for (int j = 0; j < 4; ++j) {
      int row = w * 16 + g * 4 + j;
#pragma unroll
      for (int n = 0; n < 4; ++n)
        *(unsigned short*)(Pl + ((row * 128 + (n * 16 + l16) * 2) ^ ((row & 7) << 4))) = f2bf(pr[n][j]);
    }

#pragma unroll
    for (int kk = 0; kk < 2; ++kk) {
      int prow = w * 16 + l16;
      bf16x8 fa = *(const bf16x8*)(Pl + ((prow * 128 + (kk * 32 + g * 8) * 2) ^ ((prow & 7) << 4)));
#pragma unroll
      for (int n = 0; n < 4; ++n) {
        int vrow = n * 16 + l16;
        bf16x8 fb = *(const bf16x8*)(Vl + ((vrow * 128 + (kk * 32 + g * 8) * 2) ^ ((vrow & 7) << 4)));
        yacc[n] = __builtin_amdgcn_mfma_f32_16x16x32_bf16(fa, fb, yacc[n], 0, 0, 0);
      }
    }
    __syncthreads();
  }

#pragma unroll
  for (int j = 0; j < 4; ++j) {
    float inv = 1.0f / lrun[j];
    int row = qb * 64 + w * 16 + g * 4 + j;
    unsigned short* yo = y + (bT + row) * C_DIM + h * 64;
#pragma unroll
    for (int n = 0; n < 4; ++n)
      yo[n * 16 + l16] = f2bf(yacc[n][j] * inv);
  }
}

extern "C" void kernel_launch(void* const* d_in, const int* in_sizes, int n_in,
                              void* d_out, int out_size, void* d_ws, size_t ws_size,
                              hipStream_t stream) {
  const int*   x    = (const int*)d_in[0];
  const float* tok  = (const float*)d_in[1];
  const float* pos  = (const float*)d_in[2];
  const float* wq   = (const float*)d_in[3];
  const float* bq   = (const float*)d_in[4];
  const float* wk   = (const float*)d_in[5];
  const float* bk   = (const float*)d_in[6];
  const float* wv   = (const float*)d_in[7];
  const float* bv   = (const float*)d_in[8];
  const float* wh   = (const float*)d_in[9];
  const float* bhd  = (const float*)d_in[10];
  float* out = (float*)d_out;

  char* ws = (char*)d_ws;
  size_t off = 0;
  auto alloc = [&](size_t bytes) {
    void* p = ws + off;
    off += (bytes + 255) & ~(size_t)255;
    return p;
  };
  unsigned short* h_bf    = (unsigned short*)alloc((size_t)4096 * 1024 * 2);
  unsigned short* wqkv_t  = (unsigned short*)alloc((size_t)3072 * 1024 * 2);
  float*          qbias   = (float*)alloc((size_t)3072 * 4);
  unsigned short* wh_t    = (unsigned short*)alloc((size_t)V_DIM * 1024 * 2);
  float*          qkv     = (float*)alloc((size_t)4096 * 3072 * 4);
  unsigned short* ybf     = (unsigned short*)alloc((size_t)4096 * 1024 * 2);

  embed_kernel<<<4096, 256, 0, stream>>>(x, tok, pos, h_bf);
  repack_qkv<<<dim3(4096, 3), 256, 0, stream>>>(wq, wk, wv, bq, bk, bv, wqkv_t, qbias);
  repack_whead<<<dim3(V_DIM / 64, 16), 256, 0, stream>>>(wh, wh_t);
  // QKV proj: M=4096, N=3072 -> 16 x 12 = 192 blocks (192 % 8 == 0)
  gemm256<<<192, 512, 0, stream>>>(h_bf, wqkv_t, qbias, qkv, 3072, 16);
  attn_mfma<<<dim3(T_SEQ / 64, 2 * H_N), 256, 0, stream>>>(qkv, ybf);
  // head: M=4096, N=32000 -> 16 x 125 = 2000 blocks (2000 % 8 == 0)
  gemm256<<<2000, 512, 0, stream>>>(ybf, wh_t, bhd, out, V_DIM, 16);
}